// Round 10
// baseline (216.804 us; speedup 1.0000x reference)
//
#include <hip/hip_runtime.h>
#include <math.h>

// GCN 3-layer inference. N=100000, E=3200000, feats 128->4->2->1.
// R15 = R14 (best, 211.6us) + ONE change: bucket size 256 -> 128 (R7-proven
// geometry) in the sort/degree stage:
//  - k_degree per-thread serial merge walk halves (~42 -> ~21 dependent iters)
//  - k_degree LDS 41KB -> ~25KB (6 blocks/CU), blocks 391 -> 782 (3 rounds/CU)
// Everything else byte-identical to R14 (padded int4 CSR gathers, packed oc,
// fused GEMM in k_part, wave scans, transposed lstartT, 5 dispatches).
// Edge pack: p = src | (dst&127)<<17  (src < 2^17).

#define TPB 256
#define CHUNK 4096
#define EPT (CHUNK / TPB)
#define BSZ 128             // nodes per bucket
#define SLAB2 4992          // merge cap (LDS pl capacity; mean 4096, +14 sigma)
#define SLAB2P 5376         // padded CSR region: 4992 + 128*3 pad, x4 multiple
#define NSMAX 1024

// ---- k_part: local counting sort of one 4096-edge chunk (+ fused GEMM blocks) ----
__global__ __launch_bounds__(TPB) void k_part(
    const int* __restrict__ src, const int* __restrict__ dst,
    unsigned int* __restrict__ slab, int* __restrict__ lstartT,
    const float* __restrict__ x, const float* __restrict__ W1,
    float* __restrict__ h1,
    int NB, int NS, int E, int N)
{
    __shared__ int hist[NSMAX];
    __shared__ unsigned int sorted[CHUNK];
    __shared__ int wtot[4];
    int t = threadIdx.x;

    if (blockIdx.x >= NS) {
        // ---- fused GEMM: h1 = x @ W1 (unscaled), quad-per-node ----
        float* Ws = (float*)sorted;  // alias: sort path never runs here
        for (int i = t; i < 512; i += TPB) Ws[i] = W1[i];
        __syncthreads();
        int tt = (blockIdx.x - NS) * TPB + t;
        int v = tt >> 2, p = tt & 3;
        if (v >= N) return;
        const float4* xr = (const float4*)(x + (size_t)v * 128);
        float a0 = 0.f, a1 = 0.f, a2 = 0.f, a3 = 0.f;
#pragma unroll
        for (int i = 0; i < 8; ++i) {
            int cc = p + i * 4;
            float4 xx = xr[cc];
            const float* wv = &Ws[cc * 16];
            a0 += xx.x*wv[0] + xx.y*wv[4] + xx.z*wv[8]  + xx.w*wv[12];
            a1 += xx.x*wv[1] + xx.y*wv[5] + xx.z*wv[9]  + xx.w*wv[13];
            a2 += xx.x*wv[2] + xx.y*wv[6] + xx.z*wv[10] + xx.w*wv[14];
            a3 += xx.x*wv[3] + xx.y*wv[7] + xx.z*wv[11] + xx.w*wv[15];
        }
        a0 += __shfl_xor(a0,1); a0 += __shfl_xor(a0,2);
        a1 += __shfl_xor(a1,1); a1 += __shfl_xor(a1,2);
        a2 += __shfl_xor(a2,1); a2 += __shfl_xor(a2,2);
        a3 += __shfl_xor(a3,1); a3 += __shfl_xor(a3,2);
        if (p == 0) ((float4*)h1)[v] = make_float4(a0, a1, a2, a3);
        return;
    }

    int base = blockIdx.x * CHUNK;
    int n = min(CHUNK, E - base);
    for (int i = t; i < NSMAX; i += TPB) hist[i] = 0;
    __syncthreads();
    unsigned int meta[EPT];   // d<<13 | lp   (lp < 4096 fits 13 bits; d < 2^17)
#pragma unroll
    for (int k = 0; k < EPT; ++k) {
        int li = k * TPB + t;
        if (li < n) {
            int d = dst[base + li];
            int lp = atomicAdd(&hist[d >> 7], 1);
            meta[k] = ((unsigned)d << 13) | (unsigned)lp;
        } else meta[k] = 0xFFFFFFFFu;
    }
    __syncthreads();
    // exclusive scan hist[1024]: thread t owns bins 4t..4t+3, wave scan + cross-wave
    int lane = t & 63, w = t >> 6;
    int q0 = hist[4*t], q1 = hist[4*t+1], q2 = hist[4*t+2], q3 = hist[4*t+3];
    int pq = q0 + q1 + q2 + q3, xs = pq;
    for (int d = 1; d < 64; d <<= 1) { int y = __shfl_up(xs, d); if (lane >= d) xs += y; }
    if (lane == 63) wtot[w] = xs;
    __syncthreads();
    int woff = 0;
#pragma unroll
    for (int i = 0; i < 4; ++i) if (i < w) woff += wtot[i];
    int e0 = woff + xs - pq;
    hist[4*t]   = e0;
    hist[4*t+1] = e0 + q0;
    hist[4*t+2] = e0 + q0 + q1;
    hist[4*t+3] = e0 + q0 + q1 + q2;
    __syncthreads();
#pragma unroll
    for (int k = 0; k < EPT; ++k) {
        if (meta[k] != 0xFFFFFFFFu) {
            unsigned m = meta[k];
            int d = (int)(m >> 13);
            int lp = (int)(m & 0x1FFFu);
            unsigned pk = (unsigned)src[base + k*TPB + t] | ((unsigned)(d & 127) << 17);
            sorted[hist[d >> 7] + lp] = pk;
        }
    }
    __syncthreads();
    const uint4* s4 = (const uint4*)sorted;
    uint4* g4 = (uint4*)(slab + (size_t)base);
    for (int i = t; i < CHUNK / 4; i += TPB) g4[i] = s4[i];
    // transposed lstart: hist[NB] == n (bins >= NB are empty)
    for (int i = t; i < NB + 1; i += TPB)
        lstartT[(size_t)i * NS + blockIdx.x] = hist[i];
}

// ---- k_degree: merge -> count -> padded scan -> CSR + dinv + hs1 ----
__global__ __launch_bounds__(TPB) void k_degree(
    const unsigned int* __restrict__ slab, const int* __restrict__ lstartT,
    int* __restrict__ ssrc, int2* __restrict__ oc,
    float* __restrict__ dinv, const float* __restrict__ h1, float* __restrict__ hs1,
    int NS, int NB, int N)
{
    __shared__ unsigned int pl[SLAB2];   // 19968 B
    __shared__ int slen[NSMAX];          // 4096 B (after scan: excl starts; pad = total)
    __shared__ int c[BSZ];
    __shared__ int cur[BSZ];
    __shared__ int wtot[4];
    int t = threadIdx.x, b = blockIdx.x;
    if (t < BSZ) c[t] = 0;
    int stv[NSMAX / TPB], lenv[NSMAX / TPB];
#pragma unroll
    for (int ci = 0; ci < NSMAX / TPB; ++ci) {
        int j = ci * TPB + t;
        int st = 0, len = 0;
        if (j < NS) {
            st  = lstartT[(size_t)b * NS + j];          // coalesced
            len = lstartT[(size_t)(b + 1) * NS + j] - st;
        }
        stv[ci] = st; lenv[ci] = len;
        slen[j] = len;
    }
    __syncthreads();
    // exclusive scan slen[1024] via wave scan; thread t owns 4t..4t+3
    int lane = t & 63, w = t >> 6;
    int s0 = slen[4*t], s1 = slen[4*t+1], s2 = slen[4*t+2], s3 = slen[4*t+3];
    int pq = s0 + s1 + s2 + s3, xs = pq;
    for (int d = 1; d < 64; d <<= 1) { int y = __shfl_up(xs, d); if (lane >= d) xs += y; }
    if (lane == 63) wtot[w] = xs;
    __syncthreads();
    int woff = 0;
#pragma unroll
    for (int i = 0; i < 4; ++i) if (i < w) woff += wtot[i];
    int e0 = woff + xs - pq;
    slen[4*t]   = e0;
    slen[4*t+1] = e0 + s0;
    slen[4*t+2] = e0 + s0 + s1;
    slen[4*t+3] = e0 + s0 + s1 + s2;
    __syncthreads();
    // merge segments into LDS (serial per-segment walk; ~21 iters/thread at BSZ=128)
#pragma unroll
    for (int ci = 0; ci < NSMAX / TPB; ++ci) {
        int j = ci * TPB + t;
        if (j < NS && lenv[ci] > 0) {
            int lo = slen[j];
            const unsigned int* sp = slab + (size_t)j * CHUNK + stv[ci];
            for (int k = 0; k < lenv[ci]; ++k) {
                if (lo + k >= SLAB2) break;
                pl[lo + k] = sp[k];
            }
        }
    }
    __syncthreads();
    int total = min(slen[NSMAX - 1], SLAB2);   // entries >= NS hold total (len 0)
    for (int i = t; i < total; i += TPB) atomicAdd(&c[(pl[i] >> 17) & 127], 1);
    __syncthreads();
    // scan PADDED counts -> 16B-aligned node-local offsets (wave scan;
    // t >= BSZ contributes zeros harmlessly)
    int cv = (t < BSZ) ? c[t] : 0;
    int cp = (cv + 3) & ~3;                    // pad to x4 for int4 CSR loads
    int xc = cp;
    for (int d = 1; d < 64; d <<= 1) { int y = __shfl_up(xc, d); if (lane >= d) xc += y; }
    if (lane == 63) wtot[w] = xc;
    __syncthreads();
    int woff2 = 0;
#pragma unroll
    for (int i = 0; i < 4; ++i) if (i < w) woff2 += wtot[i];
    int excl = woff2 + xc - cp;                // padded exclusive offset
    if (t < BSZ) {
        int v = (b << 7) + t;
        if (v < N) {
            oc[v] = make_int2(b * SLAB2P + excl, cv);
            float di = rsqrtf((float)(cv + 1));
            dinv[v] = di;
            float4 hv = ((const float4*)h1)[v];
            ((float4*)hs1)[v] = make_float4(di*hv.x, di*hv.y, di*hv.z, di*hv.w);
        }
        cur[t] = excl;
    }
    __syncthreads();
    // counting-sort scatter into padded bucket-local CSR region
    // (positions < total + 3*128 <= SLAB2P by construction)
    int* sb = ssrc + (size_t)b * SLAB2P;
    for (int i = t; i < total; i += TPB) {
        unsigned pk = pl[i];
        int pos = atomicAdd(&cur[(pk >> 17) & 127], 1);
        sb[pos] = (int)(pk & 0x1FFFFu);
    }
}

// ---- gathers: 8 lanes/node; ONE int4 index load per lane-iteration ----
__global__ __launch_bounds__(TPB) void k_gather1(
    const int2* __restrict__ oc, const int* __restrict__ ssrc,
    const float* __restrict__ hs1, const float* __restrict__ dinv,
    const float* __restrict__ b1, const float* __restrict__ W2,
    float* __restrict__ hs2, int n) {
    int t = blockIdx.x * TPB + threadIdx.x;
    int v = t >> 3, p = t & 7;
    if (v >= n) return;
    int2 ocv = oc[v];
    int base = ocv.x, c = ocv.y;
    const float4* H = (const float4*)hs1;
    float4 acc = make_float4(0.f, 0.f, 0.f, 0.f);
    for (int i = p * 4; i < c; i += 32) {
        int4 q = *(const int4*)(ssrc + base + i);   // 16B-aligned by construction
        bool m1 = (i + 1 < c), m2 = (i + 2 < c), m3 = (i + 3 < c);
        int e1 = m1 ? q.y : q.x;                    // clamp pad-garbage indices
        int e2 = m2 ? q.z : q.x;
        int e3 = m3 ? q.w : q.x;
        float4 h0 = H[q.x], h1v = H[e1], h2 = H[e2], h3 = H[e3];
        acc.x += h0.x; acc.y += h0.y; acc.z += h0.z; acc.w += h0.w;
        if (m1) { acc.x += h1v.x; acc.y += h1v.y; acc.z += h1v.z; acc.w += h1v.w; }
        if (m2) { acc.x += h2.x;  acc.y += h2.y;  acc.z += h2.z;  acc.w += h2.w; }
        if (m3) { acc.x += h3.x;  acc.y += h3.y;  acc.z += h3.z;  acc.w += h3.w; }
    }
    acc.x += __shfl_xor(acc.x, 1); acc.x += __shfl_xor(acc.x, 2); acc.x += __shfl_xor(acc.x, 4);
    acc.y += __shfl_xor(acc.y, 1); acc.y += __shfl_xor(acc.y, 2); acc.y += __shfl_xor(acc.y, 4);
    acc.z += __shfl_xor(acc.z, 1); acc.z += __shfl_xor(acc.z, 2); acc.z += __shfl_xor(acc.z, 4);
    acc.w += __shfl_xor(acc.w, 1); acc.w += __shfl_xor(acc.w, 2); acc.w += __shfl_xor(acc.w, 4);
    if (p == 0) {
        float4 hv = H[v];
        float di = dinv[v];
        float o0 = fmaxf(di * (acc.x + hv.x) + b1[0], 0.f);
        float o1 = fmaxf(di * (acc.y + hv.y) + b1[1], 0.f);
        float o2 = fmaxf(di * (acc.z + hv.z) + b1[2], 0.f);
        float o3 = fmaxf(di * (acc.w + hv.w) + b1[3], 0.f);
        float h0 = o0 * W2[0] + o1 * W2[2] + o2 * W2[4] + o3 * W2[6];
        float h1 = o0 * W2[1] + o1 * W2[3] + o2 * W2[5] + o3 * W2[7];
        ((float2*)hs2)[v] = make_float2(di * h0, di * h1);
    }
}

__global__ __launch_bounds__(TPB) void k_gather2(
    const int2* __restrict__ oc, const int* __restrict__ ssrc,
    const float* __restrict__ hs2, const float* __restrict__ dinv,
    const float* __restrict__ b2, const float* __restrict__ W3,
    float* __restrict__ hs3, int n) {
    int t = blockIdx.x * TPB + threadIdx.x;
    int v = t >> 3, p = t & 7;
    if (v >= n) return;
    int2 ocv = oc[v];
    int base = ocv.x, c = ocv.y;
    const float2* H = (const float2*)hs2;
    float2 acc = make_float2(0.f, 0.f);
    for (int i = p * 4; i < c; i += 32) {
        int4 q = *(const int4*)(ssrc + base + i);
        bool m1 = (i + 1 < c), m2 = (i + 2 < c), m3 = (i + 3 < c);
        int e1 = m1 ? q.y : q.x;
        int e2 = m2 ? q.z : q.x;
        int e3 = m3 ? q.w : q.x;
        float2 h0 = H[q.x], h1 = H[e1], h2 = H[e2], h3 = H[e3];
        acc.x += h0.x; acc.y += h0.y;
        if (m1) { acc.x += h1.x; acc.y += h1.y; }
        if (m2) { acc.x += h2.x; acc.y += h2.y; }
        if (m3) { acc.x += h3.x; acc.y += h3.y; }
    }
    acc.x += __shfl_xor(acc.x, 1); acc.x += __shfl_xor(acc.x, 2); acc.x += __shfl_xor(acc.x, 4);
    acc.y += __shfl_xor(acc.y, 1); acc.y += __shfl_xor(acc.y, 2); acc.y += __shfl_xor(acc.y, 4);
    if (p == 0) {
        float2 hv = H[v];
        float di = dinv[v];
        float o0 = fmaxf(di * (acc.x + hv.x) + b2[0], 0.f);
        float o1 = fmaxf(di * (acc.y + hv.y) + b2[1], 0.f);
        float h3 = o0 * W3[0] + o1 * W3[1];
        hs3[v] = di * h3;
    }
}

__global__ __launch_bounds__(TPB) void k_gather3(
    const int2* __restrict__ oc, const int* __restrict__ ssrc,
    const float* __restrict__ hs3, const float* __restrict__ dinv,
    const float* __restrict__ b3, float* __restrict__ out, int n) {
    int t = blockIdx.x * TPB + threadIdx.x;
    int v = t >> 3, p = t & 7;
    if (v >= n) return;
    int2 ocv = oc[v];
    int base = ocv.x, c = ocv.y;
    float acc = 0.f;
    for (int i = p * 4; i < c; i += 32) {
        int4 q = *(const int4*)(ssrc + base + i);
        bool m1 = (i + 1 < c), m2 = (i + 2 < c), m3 = (i + 3 < c);
        int e1 = m1 ? q.y : q.x;
        int e2 = m2 ? q.z : q.x;
        int e3 = m3 ? q.w : q.x;
        float h0 = hs3[q.x], h1 = hs3[e1], h2 = hs3[e2], h3 = hs3[e3];
        acc += h0;
        if (m1) acc += h1;
        if (m2) acc += h2;
        if (m3) acc += h3;
    }
    acc += __shfl_xor(acc, 1); acc += __shfl_xor(acc, 2); acc += __shfl_xor(acc, 4);
    if (p == 0) {
        float di = dinv[v];
        float agg = di * (acc + hs3[v]) + b3[0];
        out[v] = 1.0f / (1.0f + __expf(-agg));
    }
}

extern "C" void kernel_launch(void* const* d_in, const int* in_sizes, int n_in,
                              void* d_out, int out_size, void* d_ws, size_t ws_size,
                              hipStream_t stream) {
    const float* x  = (const float*)d_in[0];
    const int* ei   = (const int*)d_in[1];
    const float* W1 = (const float*)d_in[2];
    const float* b1 = (const float*)d_in[3];
    const float* W2 = (const float*)d_in[4];
    const float* b2 = (const float*)d_in[5];
    const float* W3 = (const float*)d_in[6];
    const float* b3 = (const float*)d_in[7];
    float* out = (float*)d_out;

    const int N = in_sizes[0] / 128;
    const int E = in_sizes[1] / 2;
    const int* src = ei;
    const int* dst = ei + E;

    const int NS = (E + CHUNK - 1) / CHUNK;   // 782 chunks
    const int NB = (N + BSZ - 1) / BSZ;       // 782 buckets of 128 nodes

    // ws carve (~36 MB). hs2/hs3 overlay the slab (dead after k_degree);
    // h1/hs1 must NOT overlay.
    char* w = (char*)d_ws;
    auto carve = [&](size_t bytes) { char* p = w; w += (bytes + 15) & ~(size_t)15; return p; };
    unsigned int* slab = (unsigned int*)carve((size_t)NS * CHUNK * 4);
    int* lstartT       = (int*)carve((size_t)(NB + 1) * NS * 4);
    int* ssrc          = (int*)carve((size_t)NB * SLAB2P * 4);
    int2* oc           = (int2*)carve((size_t)N * 8);
    float* dinv        = (float*)carve((size_t)N * 4);
    float* h1          = (float*)carve((size_t)4 * N * 4);
    float* hs1         = (float*)carve((size_t)4 * N * 4);
    float* hs2 = (float*)slab;                 // 2N floats (overlay)
    float* hs3 = hs2 + (size_t)2 * N;          // N

    const int nb1  = (4 * N + TPB - 1) / TPB;  // 1563 GEMM blocks
    const int nbN8 = (8 * N + TPB - 1) / TPB;

    k_part   <<<NS + nb1, TPB, 0, stream>>>(src, dst, slab, lstartT, x, W1, h1, NB, NS, E, N);
    k_degree <<<NB, TPB, 0, stream>>>(slab, lstartT, ssrc, oc, dinv, h1, hs1, NS, NB, N);
    k_gather1<<<nbN8, TPB, 0, stream>>>(oc, ssrc, hs1, dinv, b1, W2, hs2, N);
    k_gather2<<<nbN8, TPB, 0, stream>>>(oc, ssrc, hs2, dinv, b2, W3, hs3, N);
    k_gather3<<<nbN8, TPB, 0, stream>>>(oc, ssrc, hs3, dinv, b3, out, N);
}

// Round 11
// 206.444 us; speedup vs baseline: 1.0502x; 1.0502x over previous
//
#include <hip/hip_runtime.h>
#include <math.h>

// GCN 3-layer inference. N=100000, E=3200000, feats 128->4->2->1.
// R16 = R14 (best, 211.6us; R15's BSZ=128 reverted -- +5.2us: per-block fixed
// overhead doubles and dominates at the lean k_degree) + two k_degree edits:
//  - per-node count FUSED into the merge walk (deletes the standalone count
//    pass: a full 9216-word LDS re-read + barrier per block; R9-proven pattern)
//  - merge-walk bound check hoisted (lim = min(len, SLAB2-lo))
// Everything else byte-identical to R14 (padded int4 CSR gathers, packed oc,
// fused GEMM in k_part, wave scans, transposed lstartT, 5 dispatches).
// Edge pack: p = src | (dst&255)<<17  (src < 2^17).

#define TPB 256
#define CHUNK 4096
#define EPT (CHUNK / TPB)
#define SLAB2 9216          // merge cap (LDS pl capacity, mean 8184, +11 sigma)
#define SLAB2P 9984         // padded CSR region: 9216 + 256*3 max pad, 16B-mult
#define NSMAX 1024

// ---- k_part: local counting sort of one 4096-edge chunk (+ fused GEMM blocks) ----
__global__ __launch_bounds__(TPB) void k_part(
    const int* __restrict__ src, const int* __restrict__ dst,
    unsigned int* __restrict__ slab, int* __restrict__ lstartT,
    const float* __restrict__ x, const float* __restrict__ W1,
    float* __restrict__ h1,
    int NB, int NBP, int NS, int E, int N)
{
    __shared__ int hist[512];
    __shared__ unsigned int sorted[CHUNK];
    __shared__ int wtot[4];
    int t = threadIdx.x;

    if (blockIdx.x >= NS) {
        // ---- fused GEMM: h1 = x @ W1 (unscaled), quad-per-node ----
        float* Ws = (float*)sorted;  // alias: sort path never runs here
        for (int i = t; i < 512; i += TPB) Ws[i] = W1[i];
        __syncthreads();
        int tt = (blockIdx.x - NS) * TPB + t;
        int v = tt >> 2, p = tt & 3;
        if (v >= N) return;
        const float4* xr = (const float4*)(x + (size_t)v * 128);
        float a0 = 0.f, a1 = 0.f, a2 = 0.f, a3 = 0.f;
#pragma unroll
        for (int i = 0; i < 8; ++i) {
            int cc = p + i * 4;
            float4 xx = xr[cc];
            const float* wv = &Ws[cc * 16];
            a0 += xx.x*wv[0] + xx.y*wv[4] + xx.z*wv[8]  + xx.w*wv[12];
            a1 += xx.x*wv[1] + xx.y*wv[5] + xx.z*wv[9]  + xx.w*wv[13];
            a2 += xx.x*wv[2] + xx.y*wv[6] + xx.z*wv[10] + xx.w*wv[14];
            a3 += xx.x*wv[3] + xx.y*wv[7] + xx.z*wv[11] + xx.w*wv[15];
        }
        a0 += __shfl_xor(a0,1); a0 += __shfl_xor(a0,2);
        a1 += __shfl_xor(a1,1); a1 += __shfl_xor(a1,2);
        a2 += __shfl_xor(a2,1); a2 += __shfl_xor(a2,2);
        a3 += __shfl_xor(a3,1); a3 += __shfl_xor(a3,2);
        if (p == 0) ((float4*)h1)[v] = make_float4(a0, a1, a2, a3);
        return;
    }

    int base = blockIdx.x * CHUNK;
    int n = min(CHUNK, E - base);
    hist[t] = 0; hist[t + 256] = 0;
    __syncthreads();
    unsigned int meta[EPT];   // d<<13 | lp
#pragma unroll
    for (int k = 0; k < EPT; ++k) {
        int li = k * TPB + t;
        if (li < n) {
            int d = dst[base + li];
            int lp = atomicAdd(&hist[d >> 8], 1);
            meta[k] = ((unsigned)d << 13) | (unsigned)lp;
        } else meta[k] = 0xFFFFFFFFu;
    }
    __syncthreads();
    // exclusive scan of hist[512] via wave scan; thread t owns bins 2t, 2t+1
    int v0 = hist[2 * t], v1 = hist[2 * t + 1];
    int pr = v0 + v1;
    int xsc = pr;
    int lane = t & 63;
    for (int d = 1; d < 64; d <<= 1) {
        int y = __shfl_up(xsc, d);
        if (lane >= d) xsc += y;
    }
    if (lane == 63) wtot[t >> 6] = xsc;
    __syncthreads();
    int w = t >> 6;
    int woff = 0;
#pragma unroll
    for (int i = 0; i < 4; ++i) if (i < w) woff += wtot[i];
    int excl = woff + xsc - pr;
    hist[2 * t] = excl;
    hist[2 * t + 1] = excl + v0;
    __syncthreads();
#pragma unroll
    for (int k = 0; k < EPT; ++k) {
        if (meta[k] != 0xFFFFFFFFu) {
            unsigned m = meta[k];
            int d = (int)(m >> 13);
            int lp = (int)(m & 0x1FFFu);
            unsigned p = (unsigned)src[base + k * TPB + t] | ((unsigned)(d & 255) << 17);
            sorted[hist[d >> 8] + lp] = p;
        }
    }
    __syncthreads();
    const uint4* s4 = (const uint4*)sorted;
    uint4* g4 = (uint4*)(slab + (size_t)base);
    for (int i = t; i < CHUNK / 4; i += TPB) g4[i] = s4[i];
    // transposed: strided writes (fire-and-forget, L2-resident) buy coalesced
    // blocking reads in k_degree
    for (int i = t; i < NBP; i += TPB)
        lstartT[(size_t)i * NS + blockIdx.x] = (i < NB) ? hist[i] : n;
}

// ---- k_degree: merge(+count) -> padded scan -> CSR + dinv + hs1 ----
__global__ __launch_bounds__(TPB) void k_degree(
    const unsigned int* __restrict__ slab, const int* __restrict__ lstartT,
    int* __restrict__ ssrc, int2* __restrict__ oc,
    float* __restrict__ dinv, const float* __restrict__ h1, float* __restrict__ hs1,
    int NS, int NB, int N)
{
    __shared__ unsigned int pl[SLAB2];
    __shared__ int slen[NSMAX];
    __shared__ int c[TPB];
    __shared__ int cur[TPB];
    __shared__ int wtot[4];
    int t = threadIdx.x, b = blockIdx.x;
    c[t] = 0;
    int stv[NSMAX / TPB], lenv[NSMAX / TPB];
#pragma unroll
    for (int ci = 0; ci < NSMAX / TPB; ++ci) {
        int j = ci * TPB + t;
        int st = 0, len = 0;
        if (j < NS) {
            st  = lstartT[(size_t)b * NS + j];          // coalesced
            len = lstartT[(size_t)(b + 1) * NS + j] - st;
        }
        stv[ci] = st; lenv[ci] = len;
        slen[j] = len;
    }
    __syncthreads();
    // exclusive scan slen[1024] via wave scan; thread t owns 4t..4t+3
    int lane = t & 63, w = t >> 6;
    int s0 = slen[4*t], s1 = slen[4*t+1], s2 = slen[4*t+2], s3 = slen[4*t+3];
    int pq = s0 + s1 + s2 + s3, xs = pq;
    for (int d = 1; d < 64; d <<= 1) { int y = __shfl_up(xs, d); if (lane >= d) xs += y; }
    if (lane == 63) wtot[w] = xs;
    __syncthreads();
    int woff = 0;
#pragma unroll
    for (int i = 0; i < 4; ++i) if (i < w) woff += wtot[i];
    int e0 = woff + xs - pq;
    slen[4*t]   = e0;
    slen[4*t+1] = e0 + s0;
    slen[4*t+2] = e0 + s0 + s1;
    slen[4*t+3] = e0 + s0 + s1 + s2;
    __syncthreads();
    // merge segments into LDS + FUSED per-node count (saves a full pl re-read)
#pragma unroll
    for (int ci = 0; ci < NSMAX / TPB; ++ci) {
        int j = ci * TPB + t;
        if (j < NS && lenv[ci] > 0) {
            int lo = slen[j];
            int lim = min(lenv[ci], SLAB2 - lo);       // hoisted bound check
            const unsigned int* sp = slab + (size_t)j * CHUNK + stv[ci];
            for (int k = 0; k < lim; ++k) {
                unsigned pv = sp[k];
                pl[lo + k] = pv;
                atomicAdd(&c[(pv >> 17) & 255], 1);
            }
        }
    }
    __syncthreads();
    int total = min(slen[NSMAX - 1], SLAB2);   // entries >= NS hold total (len 0)
    // scan PADDED counts -> 16B-aligned node-local offsets (wave scan)
    int cv = c[t];
    int cp = (cv + 3) & ~3;                    // pad to x4 for int4 CSR loads
    int xc = cp;
    for (int d = 1; d < 64; d <<= 1) { int y = __shfl_up(xc, d); if (lane >= d) xc += y; }
    if (lane == 63) wtot[w] = xc;
    __syncthreads();
    int woff2 = 0;
#pragma unroll
    for (int i = 0; i < 4; ++i) if (i < w) woff2 += wtot[i];
    int excl = woff2 + xc - cp;                // padded exclusive offset
    int v = (b << 8) + t;
    if (v < N) {
        oc[v] = make_int2(b * SLAB2P + excl, cv);
        float di = rsqrtf((float)(cv + 1));
        dinv[v] = di;
        float4 hv = ((const float4*)h1)[v];
        ((float4*)hs1)[v] = make_float4(di*hv.x, di*hv.y, di*hv.z, di*hv.w);
    }
    cur[t] = excl;
    __syncthreads();
    // counting-sort scatter into padded bucket-local CSR region
    // (positions < total + 768 <= SLAB2P by construction)
    int* sb = ssrc + (size_t)b * SLAB2P;
    for (int i = t; i < total; i += TPB) {
        unsigned p = pl[i];
        int pos = atomicAdd(&cur[(p >> 17) & 255], 1);
        sb[pos] = (int)(p & 0x1FFFFu);
    }
}

// ---- gathers: 8 lanes/node; ONE int4 index load per lane-iteration ----
__global__ __launch_bounds__(TPB) void k_gather1(
    const int2* __restrict__ oc, const int* __restrict__ ssrc,
    const float* __restrict__ hs1, const float* __restrict__ dinv,
    const float* __restrict__ b1, const float* __restrict__ W2,
    float* __restrict__ hs2, int n) {
    int t = blockIdx.x * TPB + threadIdx.x;
    int v = t >> 3, p = t & 7;
    if (v >= n) return;
    int2 ocv = oc[v];
    int base = ocv.x, c = ocv.y;
    const float4* H = (const float4*)hs1;
    float4 acc = make_float4(0.f, 0.f, 0.f, 0.f);
    for (int i = p * 4; i < c; i += 32) {
        int4 q = *(const int4*)(ssrc + base + i);   // 16B-aligned by construction
        bool m1 = (i + 1 < c), m2 = (i + 2 < c), m3 = (i + 3 < c);
        int e1 = m1 ? q.y : q.x;                    // clamp pad-garbage indices
        int e2 = m2 ? q.z : q.x;
        int e3 = m3 ? q.w : q.x;
        float4 h0 = H[q.x], h1v = H[e1], h2 = H[e2], h3 = H[e3];
        acc.x += h0.x; acc.y += h0.y; acc.z += h0.z; acc.w += h0.w;
        if (m1) { acc.x += h1v.x; acc.y += h1v.y; acc.z += h1v.z; acc.w += h1v.w; }
        if (m2) { acc.x += h2.x;  acc.y += h2.y;  acc.z += h2.z;  acc.w += h2.w; }
        if (m3) { acc.x += h3.x;  acc.y += h3.y;  acc.z += h3.z;  acc.w += h3.w; }
    }
    acc.x += __shfl_xor(acc.x, 1); acc.x += __shfl_xor(acc.x, 2); acc.x += __shfl_xor(acc.x, 4);
    acc.y += __shfl_xor(acc.y, 1); acc.y += __shfl_xor(acc.y, 2); acc.y += __shfl_xor(acc.y, 4);
    acc.z += __shfl_xor(acc.z, 1); acc.z += __shfl_xor(acc.z, 2); acc.z += __shfl_xor(acc.z, 4);
    acc.w += __shfl_xor(acc.w, 1); acc.w += __shfl_xor(acc.w, 2); acc.w += __shfl_xor(acc.w, 4);
    if (p == 0) {
        float4 hv = H[v];
        float di = dinv[v];
        float o0 = fmaxf(di * (acc.x + hv.x) + b1[0], 0.f);
        float o1 = fmaxf(di * (acc.y + hv.y) + b1[1], 0.f);
        float o2 = fmaxf(di * (acc.z + hv.z) + b1[2], 0.f);
        float o3 = fmaxf(di * (acc.w + hv.w) + b1[3], 0.f);
        float h0 = o0 * W2[0] + o1 * W2[2] + o2 * W2[4] + o3 * W2[6];
        float h1 = o0 * W2[1] + o1 * W2[3] + o2 * W2[5] + o3 * W2[7];
        ((float2*)hs2)[v] = make_float2(di * h0, di * h1);
    }
}

__global__ __launch_bounds__(TPB) void k_gather2(
    const int2* __restrict__ oc, const int* __restrict__ ssrc,
    const float* __restrict__ hs2, const float* __restrict__ dinv,
    const float* __restrict__ b2, const float* __restrict__ W3,
    float* __restrict__ hs3, int n) {
    int t = blockIdx.x * TPB + threadIdx.x;
    int v = t >> 3, p = t & 7;
    if (v >= n) return;
    int2 ocv = oc[v];
    int base = ocv.x, c = ocv.y;
    const float2* H = (const float2*)hs2;
    float2 acc = make_float2(0.f, 0.f);
    for (int i = p * 4; i < c; i += 32) {
        int4 q = *(const int4*)(ssrc + base + i);
        bool m1 = (i + 1 < c), m2 = (i + 2 < c), m3 = (i + 3 < c);
        int e1 = m1 ? q.y : q.x;
        int e2 = m2 ? q.z : q.x;
        int e3 = m3 ? q.w : q.x;
        float2 h0 = H[q.x], h1 = H[e1], h2 = H[e2], h3 = H[e3];
        acc.x += h0.x; acc.y += h0.y;
        if (m1) { acc.x += h1.x; acc.y += h1.y; }
        if (m2) { acc.x += h2.x; acc.y += h2.y; }
        if (m3) { acc.x += h3.x; acc.y += h3.y; }
    }
    acc.x += __shfl_xor(acc.x, 1); acc.x += __shfl_xor(acc.x, 2); acc.x += __shfl_xor(acc.x, 4);
    acc.y += __shfl_xor(acc.y, 1); acc.y += __shfl_xor(acc.y, 2); acc.y += __shfl_xor(acc.y, 4);
    if (p == 0) {
        float2 hv = H[v];
        float di = dinv[v];
        float o0 = fmaxf(di * (acc.x + hv.x) + b2[0], 0.f);
        float o1 = fmaxf(di * (acc.y + hv.y) + b2[1], 0.f);
        float h3 = o0 * W3[0] + o1 * W3[1];
        hs3[v] = di * h3;
    }
}

__global__ __launch_bounds__(TPB) void k_gather3(
    const int2* __restrict__ oc, const int* __restrict__ ssrc,
    const float* __restrict__ hs3, const float* __restrict__ dinv,
    const float* __restrict__ b3, float* __restrict__ out, int n) {
    int t = blockIdx.x * TPB + threadIdx.x;
    int v = t >> 3, p = t & 7;
    if (v >= n) return;
    int2 ocv = oc[v];
    int base = ocv.x, c = ocv.y;
    float acc = 0.f;
    for (int i = p * 4; i < c; i += 32) {
        int4 q = *(const int4*)(ssrc + base + i);
        bool m1 = (i + 1 < c), m2 = (i + 2 < c), m3 = (i + 3 < c);
        int e1 = m1 ? q.y : q.x;
        int e2 = m2 ? q.z : q.x;
        int e3 = m3 ? q.w : q.x;
        float h0 = hs3[q.x], h1 = hs3[e1], h2 = hs3[e2], h3 = hs3[e3];
        acc += h0;
        if (m1) acc += h1;
        if (m2) acc += h2;
        if (m3) acc += h3;
    }
    acc += __shfl_xor(acc, 1); acc += __shfl_xor(acc, 2); acc += __shfl_xor(acc, 4);
    if (p == 0) {
        float di = dinv[v];
        float agg = di * (acc + hs3[v]) + b3[0];
        out[v] = 1.0f / (1.0f + __expf(-agg));
    }
}

extern "C" void kernel_launch(void* const* d_in, const int* in_sizes, int n_in,
                              void* d_out, int out_size, void* d_ws, size_t ws_size,
                              hipStream_t stream) {
    const float* x  = (const float*)d_in[0];
    const int* ei   = (const int*)d_in[1];
    const float* W1 = (const float*)d_in[2];
    const float* b1 = (const float*)d_in[3];
    const float* W2 = (const float*)d_in[4];
    const float* b2 = (const float*)d_in[5];
    const float* W3 = (const float*)d_in[6];
    const float* b3 = (const float*)d_in[7];
    float* out = (float*)d_out;

    const int N = in_sizes[0] / 128;
    const int E = in_sizes[1] / 2;
    const int* src = ei;
    const int* dst = ei + E;

    const int NS  = (E + CHUNK - 1) / CHUNK;  // 782 chunks
    const int NB  = (N + 255) >> 8;           // 391 buckets
    const int NBP = NB + 1;

    // ws carve (~34 MB). hs2/hs3 overlay the slab (dead after k_degree);
    // h1/hs1 must NOT overlay.
    char* w = (char*)d_ws;
    auto carve = [&](size_t bytes) { char* p = w; w += (bytes + 15) & ~(size_t)15; return p; };
    unsigned int* slab = (unsigned int*)carve((size_t)NS * CHUNK * 4);
    int* lstartT       = (int*)carve((size_t)NBP * NS * 4);
    int* ssrc          = (int*)carve((size_t)NB * SLAB2P * 4);
    int2* oc           = (int2*)carve((size_t)N * 8);
    float* dinv        = (float*)carve((size_t)N * 4);
    float* h1          = (float*)carve((size_t)4 * N * 4);
    float* hs1         = (float*)carve((size_t)4 * N * 4);
    float* hs2 = (float*)slab;                 // 2N floats (overlay)
    float* hs3 = hs2 + (size_t)2 * N;          // N

    const int nb1  = (4 * N + TPB - 1) / TPB;  // 1563 GEMM blocks
    const int nbN8 = (8 * N + TPB - 1) / TPB;

    k_part   <<<NS + nb1, TPB, 0, stream>>>(src, dst, slab, lstartT, x, W1, h1, NB, NBP, NS, E, N);
    k_degree <<<NB, TPB, 0, stream>>>(slab, lstartT, ssrc, oc, dinv, h1, hs1, NS, NB, N);
    k_gather1<<<nbN8, TPB, 0, stream>>>(oc, ssrc, hs1, dinv, b1, W2, hs2, N);
    k_gather2<<<nbN8, TPB, 0, stream>>>(oc, ssrc, hs2, dinv, b2, W3, hs3, N);
    k_gather3<<<nbN8, TPB, 0, stream>>>(oc, ssrc, hs3, dinv, b3, out, N);
}